// Round 8
// baseline (1802.555 us; speedup 1.0000x reference)
//
#include <hip/hip_runtime.h>

// SNN forward: T=20, B=65536, F=16; layers 16->128->128->64->10, LIF beta=0.9,
// thr=1.0, reset-subtract. Bit-exact semantics (verified r3-r7 absmax=0):
// ascending-k fmaf dot chains; spike values {0.0f,1.0f} (fmaf(1,w,a)=a+w,
// fmaf(0,w,a)=a exactly); uncontracted ((0.9*m)+c)-r LIF; strict > compares.
// r8 = r7 + amdgpu_waves_per_eu(4,4). Evidence r3/r5/r4/r6/r7: backend
// assumes 2 blocks/CU for the VGPR target (1024thr->64, 768thr->84) ignoring
// that 125KB LDS caps us at 1 block (16 waves = 4/SIMD). Pinning 4 waves/EU
// raises the cap to 128; live state ~119 -> spill traffic (4.5 GB HBM) gone.

namespace {
constexpr int kB = 65536;
constexpr int kT = 20;
constexpr int S = 8;         // batch elements per wave
constexpr int WAVES = 16;    // waves per block (1024 threads)
constexpr int NGRP = kB / S;           // 8192 groups
constexpr int TOTW = 256 * WAVES;      // 4096 waves in grid
}

__device__ __forceinline__ float ub0(unsigned u) { return (float)(u & 0xffu); }
__device__ __forceinline__ float ub1(unsigned u) { return (float)((u >> 8) & 0xffu); }
__device__ __forceinline__ float ub2(unsigned u) { return (float)((u >> 16) & 0xffu); }
__device__ __forceinline__ float ub3(unsigned u) { return (float)(u >> 24); }

__device__ __forceinline__ float fma4(const float4 s, const float4 wv, float acc) {
  acc = fmaf(s.x, wv.x, acc);
  acc = fmaf(s.y, wv.y, acc);
  acc = fmaf(s.z, wv.z, acc);
  acc = fmaf(s.w, wv.w, acc);
  return acc;
}

// 4 packed spikes -> two output rows; ascending-k per accumulator chain.
__device__ __forceinline__ void q8(unsigned pu, const float4 a, const float4 b,
                                   float& ra, float& rb) {
  float f0 = ub0(pu), f1 = ub1(pu), f2 = ub2(pu), f3 = ub3(pu);
  ra = fmaf(f0, a.x, ra); rb = fmaf(f0, b.x, rb);
  ra = fmaf(f1, a.y, ra); rb = fmaf(f1, b.y, rb);
  ra = fmaf(f2, a.z, ra); rb = fmaf(f2, b.z, rb);
  ra = fmaf(f3, a.w, ra); rb = fmaf(f3, b.w, rb);
}

__device__ __forceinline__ void q4(unsigned pu, const float4 a, float& ra) {
  ra = fmaf(ub0(pu), a.x, ra);
  ra = fmaf(ub1(pu), a.y, ra);
  ra = fmaf(ub2(pu), a.z, ra);
  ra = fmaf(ub3(pu), a.w, ra);
}

__global__ __launch_bounds__(1024)
__attribute__((amdgpu_waves_per_eu(4, 4)))
void snn_fwd(
    const float* __restrict__ x,
    const float* __restrict__ gw1,
    const float* __restrict__ gw2,
    const float* __restrict__ gw3,
    const float* __restrict__ gw4,
    float* __restrict__ out)
{
#pragma clang fp contract(off)
  // Weights chunk-XOR-swizzled (verified r3-r7): row j chunk k at (k^j).
  __shared__ __align__(16) float w1s[128 * 16];    //   8 KB
  __shared__ __align__(16) float w2s[128 * 128];   //  64 KB
  __shared__ __align__(16) float w3s[64 * 128];    //  32 KB
  __shared__ __align__(16) float w4s[10 * 64];     // 2.5 KB
  __shared__ __align__(16) unsigned char spkb[WAVES][S][128];  // 16 KB

  const int tid = threadIdx.x;

  for (int i = tid; i < 128 * 16; i += 1024) {
    int j = i >> 4, k = i & 15;
    w1s[(j << 4) + ((((k >> 2) ^ j) & 3) << 2) + (k & 3)] = gw1[i];
  }
  for (int i = tid; i < 128 * 128; i += 1024) {
    int j = i >> 7, k = i & 127;
    w2s[(j << 7) + ((((k >> 2) ^ j) & 31) << 2) + (k & 3)] = gw2[i];
  }
  for (int i = tid; i < 64 * 128; i += 1024) {
    int j = i >> 7, k = i & 127;
    w3s[(j << 7) + ((((k >> 2) ^ j) & 31) << 2) + (k & 3)] = gw3[i];
  }
  for (int i = tid; i < 640; i += 1024) w4s[i] = gw4[i];
  __syncthreads();

  const int lane = tid & 63;
  const int wv = tid >> 6;
  const int gwv = blockIdx.x * WAVES + wv;

  const int s32 = lane & 31;
  const int s4w = lane & 3;
  const float4* __restrict__ r1a = reinterpret_cast<const float4*>(w1s + (lane << 4));
  const float4* __restrict__ r1b = reinterpret_cast<const float4*>(w1s + ((64 + lane) << 4));
  const float4* __restrict__ r2a = reinterpret_cast<const float4*>(w2s + (lane << 7));
  const float4* __restrict__ r2b = reinterpret_cast<const float4*>(w2s + ((64 + lane) << 7));
  const float4* __restrict__ r3  = reinterpret_cast<const float4*>(w3s + (lane << 7));
  const float*  __restrict__ r4f = w4s + ((lane < 10 ? lane : 0) << 6);

  unsigned char* __restrict__ spb = &spkb[wv][0][0];
  const uint4* __restrict__ sp4 = reinterpret_cast<const uint4*>(spb);

  for (int grp = gwv; grp < NGRP; grp += TOTW) {
    const int bg = grp << 3;

    float m1a[S], m1b[S], m2a[S], m2b[S], m3v[S], m4v[S];
#pragma unroll
    for (int s = 0; s < S; ++s) {
      m1a[s] = 0.f; m1b[s] = 0.f; m2a[s] = 0.f; m2b[s] = 0.f; m3v[s] = 0.f; m4v[s] = 0.f;
    }

    for (int t = 0; t < kT; ++t) {
      const float4* __restrict__ xbase =
          reinterpret_cast<const float4*>(x + ((size_t)t * kB + bg) * 16);

      // ---------------- layer 1: dense fmaf, weights amortized over S
      float ca[S], cb[S];
#pragma unroll
      for (int s = 0; s < S; ++s) { ca[s] = 0.f; cb[s] = 0.f; }
#pragma unroll
      for (int c = 0; c < 4; ++c) {
        float4 wa = r1a[c ^ s4w];
        float4 wb = r1b[c ^ s4w];
#pragma unroll
        for (int s = 0; s < S; ++s) {
          float4 xs = xbase[(s << 2) + c];  // uniform addr, cache-hit
          ca[s] = fma4(xs, wa, ca[s]);
          cb[s] = fma4(xs, wb, cb[s]);
        }
      }
#pragma unroll
      for (int s = 0; s < S; ++s) {
        float rs = m1a[s] > 1.0f ? 1.0f : 0.0f;
        m1a[s] = (0.9f * m1a[s] + ca[s]) - rs;
        float rs2 = m1b[s] > 1.0f ? 1.0f : 0.0f;
        m1b[s] = (0.9f * m1b[s] + cb[s]) - rs2;
        spb[(s << 7) + lane] = (unsigned char)(m1a[s] > 1.0f);       // spk1
        spb[(s << 7) + 64 + lane] = (unsigned char)(m1b[s] > 1.0f);
      }

      // ---------------- layer 2: dense fma, 16 spikes per b128 broadcast,
      // weights loaded per-k4 (low live range)
      float aa[S], ab[S];
#pragma unroll
      for (int s = 0; s < S; ++s) { aa[s] = 0.f; ab[s] = 0.f; }
#pragma unroll 2
      for (int c = 0; c < 8; ++c) {  // k16-chunk
        uint4 P[S];
#pragma unroll
        for (int s = 0; s < S; ++s) P[s] = sp4[(s << 3) + c];  // broadcast
#pragma unroll
        for (int q = 0; q < 4; ++q) {  // k4 within chunk
          float4 wa = r2a[((c << 2) | q) ^ s32];
          float4 wb = r2b[((c << 2) | q) ^ s32];
#pragma unroll
          for (int s = 0; s < S; ++s) {
            unsigned pw = (q == 0) ? P[s].x : (q == 1) ? P[s].y : (q == 2) ? P[s].z : P[s].w;
            q8(pw, wa, wb, aa[s], ab[s]);
          }
        }
      }
#pragma unroll
      for (int s = 0; s < S; ++s) {
        float rs = m2a[s] > 1.0f ? 1.0f : 0.0f;
        m2a[s] = (0.9f * m2a[s] + aa[s]) - rs;
        float rs2 = m2b[s] > 1.0f ? 1.0f : 0.0f;
        m2b[s] = (0.9f * m2b[s] + ab[s]) - rs2;
      }
      __builtin_amdgcn_wave_barrier();  // keep spk1 reads above spk2 writes (intra-wave scheduling fence, no-op)
#pragma unroll
      for (int s = 0; s < S; ++s) {
        spb[(s << 7) + lane] = (unsigned char)(m2a[s] > 1.0f);       // spk2 overwrites spk1
        spb[(s << 7) + 64 + lane] = (unsigned char)(m2b[s] > 1.0f);
      }

      // ---------------- layer 3: dense fma, one output row per lane
      float a3[S];
#pragma unroll
      for (int s = 0; s < S; ++s) a3[s] = 0.f;
#pragma unroll 2
      for (int c = 0; c < 8; ++c) {
        uint4 P[S];
#pragma unroll
        for (int s = 0; s < S; ++s) P[s] = sp4[(s << 3) + c];
#pragma unroll
        for (int q = 0; q < 4; ++q) {
          float4 wc = r3[((c << 2) | q) ^ s32];
#pragma unroll
          for (int s = 0; s < S; ++s) {
            unsigned pw = (q == 0) ? P[s].x : (q == 1) ? P[s].y : (q == 2) ? P[s].z : P[s].w;
            q4(pw, wc, a3[s]);
          }
        }
      }

      // ---------------- LIF3 + layer 4 (sparse: ballot + ctz) + out
#pragma unroll
      for (int s = 0; s < S; ++s) {
        float rs = m3v[s] > 1.0f ? 1.0f : 0.0f;
        m3v[s] = (0.9f * m3v[s] + a3[s]) - rs;
        unsigned long long mE = __ballot(m3v[s] > 1.0f);  // spk3 (64 neurons)
        float a4 = 0.f;
        while (mE) {  // ascending-k set-bit iteration (exact chain order)
          int k = __builtin_ctzll(mE);
          mE &= mE - 1;
          a4 += r4f[k];
        }
        float rs4 = m4v[s] > 1.0f ? 1.0f : 0.0f;
        m4v[s] = (0.9f * m4v[s] + a4) - rs4;
        float s4v = m4v[s] > 1.0f ? 1.0f : 0.0f;
        if (lane < 10) out[((size_t)t * kB + bg + s) * 10 + lane] = s4v;
      }
    }
  }
}

extern "C" void kernel_launch(void* const* d_in, const int* in_sizes, int n_in,
                              void* d_out, int out_size, void* d_ws, size_t ws_size,
                              hipStream_t stream) {
  const float* x   = (const float*)d_in[0];
  const float* w1  = (const float*)d_in[1];
  const float* w2  = (const float*)d_in[2];
  const float* w3  = (const float*)d_in[3];
  const float* w4  = (const float*)d_in[4];
  float* out = (float*)d_out;
  snn_fwd<<<dim3(256), dim3(1024), 0, stream>>>(x, w1, w2, w3, w4, out);
}

// Round 9
// 1564.295 us; speedup vs baseline: 1.1523x; 1.1523x over previous
//
#include <hip/hip_runtime.h>

// SNN forward: T=20, B=65536, F=16; layers 16->128->128->64->10, LIF beta=0.9,
// thr=1.0, reset-subtract. Bit-exact semantics (verified r3-r8 absmax=0):
// ascending-k fmaf dot chains; spike values {0.0f,1.0f} (fmaf(1,w,a)=a+w,
// fmaf(0,w,a)=a exactly); uncontracted ((0.9*m)+c)-r LIF; strict > compares.
// r9: STOP fighting the 64-VGPR allocator target (r6/r7/r8 all failed to move
// it) -- fit under it instead. S=4 (24 membrane regs), no hoisted P arrays
// (spike uint2 loaded per (q2,s), 2 regs), weights 4 float4 live. ~60 live
// regs < 64 -> no scratch. LDS weight traffic doubles per element but stays
// under the VALU bound (~773us) and overlaps on the LDS pipe.

namespace {
constexpr int kB = 65536;
constexpr int kT = 20;
constexpr int S = 4;         // batch elements per wave
constexpr int WAVES = 16;    // waves per block (1024 threads)
constexpr int NGRP = kB / S;           // 16384 groups
constexpr int TOTW = 256 * WAVES;      // 4096 waves in grid
}

__device__ __forceinline__ float ub0(unsigned u) { return (float)(u & 0xffu); }
__device__ __forceinline__ float ub1(unsigned u) { return (float)((u >> 8) & 0xffu); }
__device__ __forceinline__ float ub2(unsigned u) { return (float)((u >> 16) & 0xffu); }
__device__ __forceinline__ float ub3(unsigned u) { return (float)(u >> 24); }

__device__ __forceinline__ float fma4(const float4 s, const float4 wv, float acc) {
  acc = fmaf(s.x, wv.x, acc);
  acc = fmaf(s.y, wv.y, acc);
  acc = fmaf(s.z, wv.z, acc);
  acc = fmaf(s.w, wv.w, acc);
  return acc;
}

// 4 packed u8 spikes -> two output rows; ascending-k per accumulator chain.
__device__ __forceinline__ void q8(unsigned pu, const float4 a, const float4 b,
                                   float& ra, float& rb) {
  float f0 = ub0(pu), f1 = ub1(pu), f2 = ub2(pu), f3 = ub3(pu);
  ra = fmaf(f0, a.x, ra); rb = fmaf(f0, b.x, rb);
  ra = fmaf(f1, a.y, ra); rb = fmaf(f1, b.y, rb);
  ra = fmaf(f2, a.z, ra); rb = fmaf(f2, b.z, rb);
  ra = fmaf(f3, a.w, ra); rb = fmaf(f3, b.w, rb);
}

__device__ __forceinline__ void q4(unsigned pu, const float4 a, float& ra) {
  ra = fmaf(ub0(pu), a.x, ra);
  ra = fmaf(ub1(pu), a.y, ra);
  ra = fmaf(ub2(pu), a.z, ra);
  ra = fmaf(ub3(pu), a.w, ra);
}

__global__ __launch_bounds__(1024) void snn_fwd(
    const float* __restrict__ x,
    const float* __restrict__ gw1,
    const float* __restrict__ gw2,
    const float* __restrict__ gw3,
    const float* __restrict__ gw4,
    float* __restrict__ out)
{
#pragma clang fp contract(off)
  // Weights chunk-XOR-swizzled (verified r3-r8): row j chunk k at (k^j).
  __shared__ __align__(16) float w1s[128 * 16];    //   8 KB
  __shared__ __align__(16) float w2s[128 * 128];   //  64 KB
  __shared__ __align__(16) float w3s[64 * 128];    //  32 KB
  __shared__ __align__(16) float w4s[10 * 64];     // 2.5 KB
  __shared__ __align__(16) unsigned char spkb[WAVES][S][128];  // 8 KB

  const int tid = threadIdx.x;

  for (int i = tid; i < 128 * 16; i += 1024) {
    int j = i >> 4, k = i & 15;
    w1s[(j << 4) + ((((k >> 2) ^ j) & 3) << 2) + (k & 3)] = gw1[i];
  }
  for (int i = tid; i < 128 * 128; i += 1024) {
    int j = i >> 7, k = i & 127;
    w2s[(j << 7) + ((((k >> 2) ^ j) & 31) << 2) + (k & 3)] = gw2[i];
  }
  for (int i = tid; i < 64 * 128; i += 1024) {
    int j = i >> 7, k = i & 127;
    w3s[(j << 7) + ((((k >> 2) ^ j) & 31) << 2) + (k & 3)] = gw3[i];
  }
  for (int i = tid; i < 640; i += 1024) w4s[i] = gw4[i];
  __syncthreads();

  const int lane = tid & 63;
  const int wv = tid >> 6;
  const int gwv = blockIdx.x * WAVES + wv;

  const int s32 = lane & 31;
  const int s4w = lane & 3;
  const float4* __restrict__ r1a = reinterpret_cast<const float4*>(w1s + (lane << 4));
  const float4* __restrict__ r1b = reinterpret_cast<const float4*>(w1s + ((64 + lane) << 4));
  const float4* __restrict__ r2a = reinterpret_cast<const float4*>(w2s + (lane << 7));
  const float4* __restrict__ r2b = reinterpret_cast<const float4*>(w2s + ((64 + lane) << 7));
  const float4* __restrict__ r3  = reinterpret_cast<const float4*>(w3s + (lane << 7));
  const float*  __restrict__ r4f = w4s + ((lane < 10 ? lane : 0) << 6);

  unsigned char* __restrict__ spb = &spkb[wv][0][0];
  const uint2* __restrict__ sp2 = reinterpret_cast<const uint2*>(spb);  // 8 spikes/read

  for (int grp = gwv; grp < NGRP; grp += TOTW) {
    const int bg = grp << 2;

    float m1a[S], m1b[S], m2a[S], m2b[S], m3v[S], m4v[S];
#pragma unroll
    for (int s = 0; s < S; ++s) {
      m1a[s] = 0.f; m1b[s] = 0.f; m2a[s] = 0.f; m2b[s] = 0.f; m3v[s] = 0.f; m4v[s] = 0.f;
    }

    for (int t = 0; t < kT; ++t) {
      const float4* __restrict__ xbase =
          reinterpret_cast<const float4*>(x + ((size_t)t * kB + bg) * 16);

      // ---------------- layer 1: dense fmaf, weights amortized over S
      float ca[S], cb[S];
#pragma unroll
      for (int s = 0; s < S; ++s) { ca[s] = 0.f; cb[s] = 0.f; }
#pragma unroll
      for (int c = 0; c < 4; ++c) {
        float4 wa = r1a[c ^ s4w];
        float4 wb = r1b[c ^ s4w];
#pragma unroll
        for (int s = 0; s < S; ++s) {
          float4 xs = xbase[(s << 2) + c];  // uniform addr load
          ca[s] = fma4(xs, wa, ca[s]);
          cb[s] = fma4(xs, wb, cb[s]);
        }
      }
#pragma unroll
      for (int s = 0; s < S; ++s) {
        float rs = m1a[s] > 1.0f ? 1.0f : 0.0f;
        m1a[s] = (0.9f * m1a[s] + ca[s]) - rs;
        float rs2 = m1b[s] > 1.0f ? 1.0f : 0.0f;
        m1b[s] = (0.9f * m1b[s] + cb[s]) - rs2;
        spb[(s << 7) + lane] = (unsigned char)(m1a[s] > 1.0f);       // spk1
        spb[(s << 7) + 64 + lane] = (unsigned char)(m1b[s] > 1.0f);
      }

      // ---------------- layer 2: dense fma; per-q2 weight loads (low liveness),
      // one uint2 spike broadcast (8 spikes) per (q2,s)
      float aa[S], ab[S];
#pragma unroll
      for (int s = 0; s < S; ++s) { aa[s] = 0.f; ab[s] = 0.f; }
#pragma unroll 2
      for (int q2 = 0; q2 < 16; ++q2) {  // 8-spike step
        float4 wa0 = r2a[(q2 << 1) ^ s32];
        float4 wb0 = r2b[(q2 << 1) ^ s32];
        float4 wa1 = r2a[((q2 << 1) | 1) ^ s32];
        float4 wb1 = r2b[((q2 << 1) | 1) ^ s32];
#pragma unroll
        for (int s = 0; s < S; ++s) {
          uint2 pu = sp2[(s << 4) + q2];   // broadcast (uniform addr)
          q8(pu.x, wa0, wb0, aa[s], ab[s]);
          q8(pu.y, wa1, wb1, aa[s], ab[s]);
        }
      }
#pragma unroll
      for (int s = 0; s < S; ++s) {
        float rs = m2a[s] > 1.0f ? 1.0f : 0.0f;
        m2a[s] = (0.9f * m2a[s] + aa[s]) - rs;
        float rs2 = m2b[s] > 1.0f ? 1.0f : 0.0f;
        m2b[s] = (0.9f * m2b[s] + ab[s]) - rs2;
      }
      __builtin_amdgcn_wave_barrier();  // keep spk1 reads above spk2 writes
#pragma unroll
      for (int s = 0; s < S; ++s) {
        spb[(s << 7) + lane] = (unsigned char)(m2a[s] > 1.0f);       // spk2
        spb[(s << 7) + 64 + lane] = (unsigned char)(m2b[s] > 1.0f);
      }

      // ---------------- layer 3: dense fma, one output row per lane
      float a3[S];
#pragma unroll
      for (int s = 0; s < S; ++s) a3[s] = 0.f;
#pragma unroll 2
      for (int q2 = 0; q2 < 16; ++q2) {
        float4 wc0 = r3[(q2 << 1) ^ s32];
        float4 wc1 = r3[((q2 << 1) | 1) ^ s32];
#pragma unroll
        for (int s = 0; s < S; ++s) {
          uint2 pu = sp2[(s << 4) + q2];
          q4(pu.x, wc0, a3[s]);
          q4(pu.y, wc1, a3[s]);
        }
      }

      // ---------------- LIF3 + layer 4 (sparse: ballot + ctz) + out
#pragma unroll
      for (int s = 0; s < S; ++s) {
        float rs = m3v[s] > 1.0f ? 1.0f : 0.0f;
        m3v[s] = (0.9f * m3v[s] + a3[s]) - rs;
        unsigned long long mE = __ballot(m3v[s] > 1.0f);  // spk3 (64 neurons)
        float a4 = 0.f;
        while (mE) {  // ascending-k set-bit iteration (exact chain order)
          int k = __builtin_ctzll(mE);
          mE &= mE - 1;
          a4 += r4f[k];
        }
        float rs4 = m4v[s] > 1.0f ? 1.0f : 0.0f;
        m4v[s] = (0.9f * m4v[s] + a4) - rs4;
        float s4v = m4v[s] > 1.0f ? 1.0f : 0.0f;
        if (lane < 10) out[((size_t)t * kB + bg + s) * 10 + lane] = s4v;
      }
    }
  }
}

extern "C" void kernel_launch(void* const* d_in, const int* in_sizes, int n_in,
                              void* d_out, int out_size, void* d_ws, size_t ws_size,
                              hipStream_t stream) {
  const float* x   = (const float*)d_in[0];
  const float* w1  = (const float*)d_in[1];
  const float* w2  = (const float*)d_in[2];
  const float* w3  = (const float*)d_in[3];
  const float* w4  = (const float*)d_in[4];
  float* out = (float*)d_out;
  snn_fwd<<<dim3(256), dim3(1024), 0, stream>>>(x, w1, w2, w3, w4, out);
}